// Round 3
// baseline (161.369 us; speedup 1.0000x reference)
//
#include <hip/hip_runtime.h>

#define N_TOKENS 32768
#define K_CODES  1024
#define DIM      256
#define BETA     0.25f

typedef unsigned long long u64;
typedef _Float16 half8 __attribute__((ext_vector_type(8)));
typedef float floatx4 __attribute__((ext_vector_type(4)));

// ---- init: wn[k]=||w_k||^2 (fp32 exact), counts=0, keys=+inf, w->hi/lo fp16 --
__global__ void init_kernel(const float* __restrict__ w, float* __restrict__ wn,
                            int* __restrict__ counts, u64* __restrict__ keys,
                            _Float16* __restrict__ whiG, _Float16* __restrict__ wloG) {
    int k = blockIdx.x;
    int lane = threadIdx.x;  // 64
    float4 v = *(const float4*)(w + (size_t)k * DIM + lane * 4);
    float vals[4] = {v.x, v.y, v.z, v.w};
    float s = 0.f;
    #pragma unroll
    for (int e = 0; e < 4; e++) {
        s += vals[e] * vals[e];
        _Float16 h = (_Float16)vals[e];
        whiG[k * DIM + lane * 4 + e] = h;
        wloG[k * DIM + lane * 4 + e] = (_Float16)(vals[e] - (float)h);
    }
    #pragma unroll
    for (int off = 32; off; off >>= 1) s += __shfl_down(s, off);
    if (lane == 0) { wn[k] = s; counts[k] = 0; }
    if (lane < 32) keys[k * 32 + lane] = ~0ull;   // 1024*32 = 32768 keys
}

// ---------------- argmin: fp16-split MFMA distance GEMM + atomicMin merge ----
// dot(z,w) = hi_z*hi_w + hi_z*lo_w + lo_z*hi_w  (lo*lo dropped, err ~1e-5).
// grid = 4 code-quarters x 256 token-tiles. Block: 128 tok x 256 codes,
// 4 waves, wave tile 64x128. Same verified math/layout as the 159 us
// baseline (ZS=40 rows: b128 accesses at the structural 8-words/bank min).
// Schedule change (T14 issue-early/write-late, NO global_load_lds — the DMA
// variant killed the container twice, suspected addrspace-cast fault):
//   top of iter dt:  issue global loads for chunk dt+1 into regs
//   MFMA block on chunk dt          <- ~3.7k cycles hide the load latency
//   barrier; convert+write dt+1 to LDS; barrier
// VGPR ~220 (acc 128 + staging 48 + frags): under the (256,2) 256 cap;
// spill check = WRITE_SIZE stays ~MB-scale.
__global__ __launch_bounds__(256, 2) void argmin_kernel(
    const float* __restrict__ z, const _Float16* __restrict__ whiG,
    const _Float16* __restrict__ wloG, const float* __restrict__ wn,
    u64* __restrict__ keys)
{
    constexpr int ZS = 40;   // halves per row (80 B, 16-B aligned)
    __shared__ _Float16 zhi[128 * ZS], zlo[128 * ZS];
    __shared__ _Float16 whi[256 * ZS], wlo[256 * ZS];

    const int tid  = threadIdx.x;
    const int lane = tid & 63;
    const int wid  = tid >> 6;          // 0..3
    const int wm   = wid >> 1;          // token half (64)
    const int wq   = wid & 1;           // code half (128)
    const int t_   = blockIdx.x & 255;  // token tile
    const int q    = blockIdx.x >> 8;   // code quarter 0..3
    const int tok0  = t_ * 128;
    const int kbase = q * 256;

    // ||w||^2 for this thread's 8 epilogue columns -> registers
    float wnr[8];
    #pragma unroll
    for (int j = 0; j < 8; j++)
        wnr[j] = wn[kbase + wq * 128 + j * 16 + (lane & 15)];

    floatx4 acc[4][8];
    #pragma unroll
    for (int i = 0; i < 4; i++)
        #pragma unroll
        for (int j = 0; j < 8; j++)
            acc[i][j] = (floatx4){0.f, 0.f, 0.f, 0.f};

    const int r0 = tid >> 2;   // staging row (0..63)
    const int g0 = tid & 3;    // 8-half group within 32-chunk

    // in-flight staging registers for chunk dt+1
    float zr[16];
    half8 wh[4], wl[4];

    auto load_chunk = [&](int dt) {
        const int d0 = dt * 32;
        #pragma unroll
        for (int s = 0; s < 2; s++) {
            const float* p = z + (size_t)(tok0 + r0 + s * 64) * DIM + d0 + g0 * 8;
            float4 a = *(const float4*)p;
            float4 b = *(const float4*)(p + 4);
            zr[s * 8 + 0] = a.x; zr[s * 8 + 1] = a.y; zr[s * 8 + 2] = a.z; zr[s * 8 + 3] = a.w;
            zr[s * 8 + 4] = b.x; zr[s * 8 + 5] = b.y; zr[s * 8 + 6] = b.z; zr[s * 8 + 7] = b.w;
        }
        #pragma unroll
        for (int s = 0; s < 4; s++) {
            size_t goff = (size_t)(kbase + r0 + s * 64) * DIM + d0 + g0 * 8;
            wh[s] = *(const half8*)&whiG[goff];
            wl[s] = *(const half8*)&wloG[goff];
        }
    };
    auto write_chunk = [&]() {
        #pragma unroll
        for (int s = 0; s < 2; s++) {
            int t = r0 + s * 64;
            half8 hv, lv;
            #pragma unroll
            for (int e = 0; e < 8; e++) {
                _Float16 h = (_Float16)zr[s * 8 + e];
                hv[e] = h;
                lv[e] = (_Float16)(zr[s * 8 + e] - (float)h);
            }
            *(half8*)&zhi[t * ZS + g0 * 8] = hv;
            *(half8*)&zlo[t * ZS + g0 * 8] = lv;
        }
        #pragma unroll
        for (int s = 0; s < 4; s++) {
            int t = r0 + s * 64;
            *(half8*)&whi[t * ZS + g0 * 8] = wh[s];
            *(half8*)&wlo[t * ZS + g0 * 8] = wl[s];
        }
    };

    // prologue: chunk 0 staged serially
    load_chunk(0);
    write_chunk();
    __syncthreads();

    for (int dt = 0; dt < 8; ++dt) {
        if (dt < 7) load_chunk(dt + 1);   // loads fly under the MFMA block

        // fragments: A[m=lane&15][k=(lane>>4)*8+e], B[k][n=lane&15]
        const int koff = (lane >> 4) * 8;
        half8 ah[4], al[4];
        #pragma unroll
        for (int i = 0; i < 4; i++) {
            int off = (wm * 64 + i * 16 + (lane & 15)) * ZS + koff;
            ah[i] = *(const half8*)&zhi[off];
            al[i] = *(const half8*)&zlo[off];
        }
        #pragma unroll
        for (int j = 0; j < 8; j++) {
            int off = (wq * 128 + j * 16 + (lane & 15)) * ZS + koff;
            half8 bh = *(const half8*)&whi[off];
            half8 bl = *(const half8*)&wlo[off];
            #pragma unroll
            for (int i = 0; i < 4; i++) {
                acc[i][j] = __builtin_amdgcn_mfma_f32_16x16x32_f16(ah[i], bh, acc[i][j], 0, 0, 0);
                acc[i][j] = __builtin_amdgcn_mfma_f32_16x16x32_f16(ah[i], bl, acc[i][j], 0, 0, 0);
                acc[i][j] = __builtin_amdgcn_mfma_f32_16x16x32_f16(al[i], bh, acc[i][j], 0, 0, 0);
            }
        }
        __syncthreads();               // all LDS reads of chunk dt done
        if (dt < 7) write_chunk();     // convert + write chunk dt+1
        __syncthreads();               // chunk dt+1 visible
    }

    // epilogue: dist = wn[code] - 2*dot (||z||^2 constant per row).
    // C layout: col(code) = lane&15, row(token) = (lane>>4)*4 + reg.
    #pragma unroll
    for (int i = 0; i < 4; i++) {
        #pragma unroll
        for (int r = 0; r < 4; r++) {
            float bv = 3.4e38f; int bi = 0;
            #pragma unroll
            for (int j = 0; j < 8; j++) {
                int cl = wq * 128 + j * 16 + (lane & 15);
                float dist = wnr[j] - 2.0f * acc[i][j][r];
                if (dist < bv) { bv = dist; bi = kbase + cl; }
            }
            unsigned uu = __float_as_uint(bv);
            unsigned ss = (uu & 0x80000000u) ? ~uu : (uu | 0x80000000u);
            u64 key = ((u64)ss << 32) | (unsigned)bi;
            #pragma unroll
            for (int m = 1; m < 16; m <<= 1) {
                u64 o = __shfl_xor(key, m);
                if (o < key) key = o;
            }
            if ((lane & 15) == 0) {
                int token = tok0 + wm * 64 + i * 16 + (lane >> 4) * 4 + r;
                atomicMin(&keys[token], key);
            }
        }
    }
}

// ---------------- gather + commitment loss + idx/counts ----------------
// wave (64 lanes) = one token (64 float4). 8192 waves x 4 iters.
// k masked to 10 bits: valid keys always carry code < 1024; converts any
// upstream failure into a clean numeric mismatch instead of a wild gather
// -> memory fault -> dead container.
__global__ void gather_loss_kernel(const float* __restrict__ z,
                                   const float* __restrict__ w,
                                   const u64* __restrict__ keys,
                                   float* __restrict__ zq_out,
                                   float* __restrict__ idxf,
                                   int* __restrict__ counts,
                                   float* __restrict__ partials)
{
    __shared__ float red[4];
    int tid = threadIdx.x;
    int lane = tid & 63;
    int wid = blockIdx.x * 4 + (tid >> 6);   // 0..8191
    float s = 0.0f;
    #pragma unroll
    for (int it = 0; it < 4; it++) {
        int tok = wid + it * 8192;
        u64 key = 0;
        if (lane == 0) key = keys[tok];
        key = __shfl(key, 0);
        int k = (int)(key & (u64)(K_CODES - 1));
        float4 wv = *(const float4*)(w + (size_t)k * DIM + lane * 4);
        float4 zv = *(const float4*)(z + (size_t)tok * DIM + lane * 4);
        *(float4*)(zq_out + (size_t)tok * DIM + lane * 4) = wv;
        float dx = wv.x - zv.x, dy = wv.y - zv.y, dz = wv.z - zv.z, dw = wv.w - zv.w;
        s += dx * dx + dy * dy + dz * dz + dw * dw;
        if (lane == 0) {
            idxf[tok] = (float)k;
            atomicAdd(&counts[k], 1);
        }
    }
    #pragma unroll
    for (int off = 32; off; off >>= 1) s += __shfl_down(s, off);
    if (lane == 0) red[tid >> 6] = s;
    __syncthreads();
    if (tid == 0)
        partials[blockIdx.x] = red[0] + red[1] + red[2] + red[3];
}

// ---------------- perplexity + loss finalize ----------------
__global__ void finalize_kernel(const int* __restrict__ counts,
                                const float* __restrict__ partials,
                                float* __restrict__ loss_out,
                                float* __restrict__ ppl_out)
{
    __shared__ float redE[16], redL[16];
    int tid = threadIdx.x;  // 1024
    float e = (float)counts[tid] * (1.0f / (float)N_TOKENS);
    float t = -e * logf(e + 1e-10f);
    float p = partials[tid] + partials[tid + 1024];
    #pragma unroll
    for (int off = 32; off; off >>= 1) {
        t += __shfl_down(t, off);
        p += __shfl_down(p, off);
    }
    if ((tid & 63) == 0) { redE[tid >> 6] = t; redL[tid >> 6] = p; }
    __syncthreads();
    if (tid == 0) {
        float se = 0.0f, sl = 0.0f;
        #pragma unroll
        for (int i = 0; i < 16; i++) { se += redE[i]; sl += redL[i]; }
        *ppl_out = expf(se);
        *loss_out = BETA * sl / (float)((size_t)N_TOKENS * DIM);
    }
}

extern "C" void kernel_launch(void* const* d_in, const int* in_sizes, int n_in,
                              void* d_out, int out_size, void* d_ws, size_t ws_size,
                              hipStream_t stream) {
    const float* z = (const float*)d_in[0];
    const float* w = (const float*)d_in[1];
    float* out = (float*)d_out;

    // d_out layout (float): [0]=loss, [1..NT*D]=z_q_st, [..]=indices(float), [last]=perplexity
    float* loss_out = out;
    float* zq_out   = out + 1;
    float* idxf     = out + 1 + (size_t)N_TOKENS * DIM;
    float* ppl_out  = out + (out_size - 1);

    // ws layout: wn f32[1024] | counts i32[1024] | partials f32[2048]
    //            | keys u64[32768] @ byte 16384 | whiG/wloG fp16[1024*256] @ 278528
    float* wn       = (float*)d_ws;
    int*   counts   = (int*)d_ws + 1024;
    float* partials = (float*)d_ws + 2048;
    u64*   keys     = (u64*)((char*)d_ws + 16384);
    _Float16* whiG  = (_Float16*)((char*)d_ws + 16384 + (size_t)N_TOKENS * 8);
    _Float16* wloG  = whiG + (size_t)K_CODES * DIM;

    init_kernel<<<K_CODES, 64, 0, stream>>>(w, wn, counts, keys, whiG, wloG);
    argmin_kernel<<<4 * 256, 256, 0, stream>>>(z, whiG, wloG, wn, keys);
    gather_loss_kernel<<<2048, 256, 0, stream>>>(z, w, keys, zq_out, idxf, counts, partials);
    finalize_kernel<<<1, 1024, 0, stream>>>(counts, partials, loss_out, ppl_out);
}

// Round 4
// 160.280 us; speedup vs baseline: 1.0068x; 1.0068x over previous
//
#include <hip/hip_runtime.h>

#define N_TOKENS 32768
#define K_CODES  1024
#define DIM      256
#define BETA     0.25f

typedef unsigned long long u64;
typedef _Float16 half8 __attribute__((ext_vector_type(8)));
typedef float floatx4 __attribute__((ext_vector_type(4)));

// ---- init: wn[k]=||w_k||^2 (fp32 exact), counts=0, keys=+inf, w->hi/lo fp16 --
__global__ void init_kernel(const float* __restrict__ w, float* __restrict__ wn,
                            int* __restrict__ counts, u64* __restrict__ keys,
                            _Float16* __restrict__ whiG, _Float16* __restrict__ wloG) {
    int k = blockIdx.x;
    int lane = threadIdx.x;  // 64
    float4 v = *(const float4*)(w + (size_t)k * DIM + lane * 4);
    float vals[4] = {v.x, v.y, v.z, v.w};
    float s = 0.f;
    #pragma unroll
    for (int e = 0; e < 4; e++) {
        s += vals[e] * vals[e];
        _Float16 h = (_Float16)vals[e];
        whiG[k * DIM + lane * 4 + e] = h;
        wloG[k * DIM + lane * 4 + e] = (_Float16)(vals[e] - (float)h);
    }
    #pragma unroll
    for (int off = 32; off; off >>= 1) s += __shfl_down(s, off);
    if (lane == 0) { wn[k] = s; counts[k] = 0; }
    if (lane < 32) keys[k * 32 + lane] = ~0ull;   // 1024*32 = 32768 keys
}

// ---------------- argmin: fp16-split MFMA distance GEMM + atomicMin merge ----
// dot(z,w) = hi_z*hi_w + hi_z*lo_w + lo_z*hi_w  (lo*lo dropped, err ~1e-5).
// grid = 4 code-quarters x 256 token-tiles. Block: 128 tok x 256 codes,
// 4 waves, wave tile 64x128. EXACT r0 serial-stage schedule (measured 64 us;
// the T14 issue-early variant regressed to 80 us: acc=128 AGPR + ~120 VGPR
// leaves no headroom for live staging regs at (256,2), so the compiler sinks
// the loads and degrades the schedule — round-3 lesson). One addition:
// T5 s_setprio around the MFMA cluster. The 2 resident blocks/CU run at
// independent phases (one staging while the other does MFMA) — exactly the
// wave-role diversity setprio needs (m191 attn regime, not m190's lockstep).
__global__ __launch_bounds__(256, 2) void argmin_kernel(
    const float* __restrict__ z, const _Float16* __restrict__ whiG,
    const _Float16* __restrict__ wloG, const float* __restrict__ wn,
    u64* __restrict__ keys)
{
    constexpr int ZS = 40;   // halves per row (80 B, 16-B aligned)
    __shared__ _Float16 zhi[128 * ZS], zlo[128 * ZS];
    __shared__ _Float16 whi[256 * ZS], wlo[256 * ZS];

    const int tid  = threadIdx.x;
    const int lane = tid & 63;
    const int wid  = tid >> 6;          // 0..3
    const int wm   = wid >> 1;          // token half (64)
    const int wq   = wid & 1;           // code half (128)
    const int t_   = blockIdx.x & 255;  // token tile
    const int q    = blockIdx.x >> 8;   // code quarter 0..3
    const int tok0  = t_ * 128;
    const int kbase = q * 256;

    // ||w||^2 for this thread's 8 epilogue columns -> registers (r3-verified)
    float wnr[8];
    #pragma unroll
    for (int j = 0; j < 8; j++)
        wnr[j] = wn[kbase + wq * 128 + j * 16 + (lane & 15)];

    floatx4 acc[4][8];
    #pragma unroll
    for (int i = 0; i < 4; i++)
        #pragma unroll
        for (int j = 0; j < 8; j++)
            acc[i][j] = (floatx4){0.f, 0.f, 0.f, 0.f};

    const int r0 = tid >> 2;   // staging row (0..63)
    const int g0 = tid & 3;    // 8-half group within 32-chunk

    for (int dt = 0; dt < 8; ++dt) {
        const int d0 = dt * 32;
        __syncthreads();   // previous chunk's fragment reads done

        // stage z chunk (128 tok x 32 d): fp32 -> (hi,lo) fp16
        #pragma unroll
        for (int s = 0; s < 2; s++) {
            int t = r0 + s * 64;
            const float* p = z + (size_t)(tok0 + t) * DIM + d0 + g0 * 8;
            float4 a = *(const float4*)p;
            float4 b = *(const float4*)(p + 4);
            float vals[8] = {a.x, a.y, a.z, a.w, b.x, b.y, b.z, b.w};
            half8 hv, lv;
            #pragma unroll
            for (int e = 0; e < 8; e++) {
                _Float16 h = (_Float16)vals[e];
                hv[e] = h;
                lv[e] = (_Float16)(vals[e] - (float)h);
            }
            *(half8*)&zhi[t * ZS + g0 * 8] = hv;
            *(half8*)&zlo[t * ZS + g0 * 8] = lv;
        }
        // stage w chunk (256 codes x 32 d): pre-split fp16, pure copy
        #pragma unroll
        for (int s = 0; s < 4; s++) {
            int t = r0 + s * 64;
            size_t goff = (size_t)(kbase + t) * DIM + d0 + g0 * 8;
            *(half8*)&whi[t * ZS + g0 * 8] = *(const half8*)&whiG[goff];
            *(half8*)&wlo[t * ZS + g0 * 8] = *(const half8*)&wloG[goff];
        }
        __syncthreads();

        // fragments: A[m=lane&15][k=(lane>>4)*8+e], B[k][n=lane&15]
        const int koff = (lane >> 4) * 8;
        half8 ah[4], al[4];
        #pragma unroll
        for (int i = 0; i < 4; i++) {
            int off = (wm * 64 + i * 16 + (lane & 15)) * ZS + koff;
            ah[i] = *(const half8*)&zhi[off];
            al[i] = *(const half8*)&zlo[off];
        }
        __builtin_amdgcn_s_setprio(1);   // T5: favor MFMA-phase waves
        #pragma unroll
        for (int j = 0; j < 8; j++) {
            int off = (wq * 128 + j * 16 + (lane & 15)) * ZS + koff;
            half8 bh = *(const half8*)&whi[off];
            half8 bl = *(const half8*)&wlo[off];
            #pragma unroll
            for (int i = 0; i < 4; i++) {
                acc[i][j] = __builtin_amdgcn_mfma_f32_16x16x32_f16(ah[i], bh, acc[i][j], 0, 0, 0);
                acc[i][j] = __builtin_amdgcn_mfma_f32_16x16x32_f16(ah[i], bl, acc[i][j], 0, 0, 0);
                acc[i][j] = __builtin_amdgcn_mfma_f32_16x16x32_f16(al[i], bh, acc[i][j], 0, 0, 0);
            }
        }
        __builtin_amdgcn_s_setprio(0);
    }

    // epilogue: dist = wn[code] - 2*dot (||z||^2 constant per row).
    // C layout: col(code) = lane&15, row(token) = (lane>>4)*4 + reg.
    #pragma unroll
    for (int i = 0; i < 4; i++) {
        #pragma unroll
        for (int r = 0; r < 4; r++) {
            float bv = 3.4e38f; int bi = 0;
            #pragma unroll
            for (int j = 0; j < 8; j++) {
                int cl = wq * 128 + j * 16 + (lane & 15);
                float dist = wnr[j] - 2.0f * acc[i][j][r];
                if (dist < bv) { bv = dist; bi = kbase + cl; }
            }
            unsigned uu = __float_as_uint(bv);
            unsigned ss = (uu & 0x80000000u) ? ~uu : (uu | 0x80000000u);
            u64 key = ((u64)ss << 32) | (unsigned)bi;
            #pragma unroll
            for (int m = 1; m < 16; m <<= 1) {
                u64 o = __shfl_xor(key, m);
                if (o < key) key = o;
            }
            if ((lane & 15) == 0) {
                int token = tok0 + wm * 64 + i * 16 + (lane >> 4) * 4 + r;
                atomicMin(&keys[token], key);
            }
        }
    }
}

// ---------------- gather + commitment loss + idx/counts ----------------
// wave (64 lanes) = one token (64 float4). 8192 waves x 4 iters.
// k masked to 10 bits: valid keys always carry code < 1024; converts any
// upstream failure into a clean numeric mismatch instead of a wild gather
// -> memory fault -> dead container (round-1/2 lesson).
__global__ void gather_loss_kernel(const float* __restrict__ z,
                                   const float* __restrict__ w,
                                   const u64* __restrict__ keys,
                                   float* __restrict__ zq_out,
                                   float* __restrict__ idxf,
                                   int* __restrict__ counts,
                                   float* __restrict__ partials)
{
    __shared__ float red[4];
    int tid = threadIdx.x;
    int lane = tid & 63;
    int wid = blockIdx.x * 4 + (tid >> 6);   // 0..8191
    float s = 0.0f;
    #pragma unroll
    for (int it = 0; it < 4; it++) {
        int tok = wid + it * 8192;
        u64 key = 0;
        if (lane == 0) key = keys[tok];
        key = __shfl(key, 0);
        int k = (int)(key & (u64)(K_CODES - 1));
        float4 wv = *(const float4*)(w + (size_t)k * DIM + lane * 4);
        float4 zv = *(const float4*)(z + (size_t)tok * DIM + lane * 4);
        *(float4*)(zq_out + (size_t)tok * DIM + lane * 4) = wv;
        float dx = wv.x - zv.x, dy = wv.y - zv.y, dz = wv.z - zv.z, dw = wv.w - zv.w;
        s += dx * dx + dy * dy + dz * dz + dw * dw;
        if (lane == 0) {
            idxf[tok] = (float)k;
            atomicAdd(&counts[k], 1);
        }
    }
    #pragma unroll
    for (int off = 32; off; off >>= 1) s += __shfl_down(s, off);
    if (lane == 0) red[tid >> 6] = s;
    __syncthreads();
    if (tid == 0)
        partials[blockIdx.x] = red[0] + red[1] + red[2] + red[3];
}

// ---------------- perplexity + loss finalize ----------------
__global__ void finalize_kernel(const int* __restrict__ counts,
                                const float* __restrict__ partials,
                                float* __restrict__ loss_out,
                                float* __restrict__ ppl_out)
{
    __shared__ float redE[16], redL[16];
    int tid = threadIdx.x;  // 1024
    float e = (float)counts[tid] * (1.0f / (float)N_TOKENS);
    float t = -e * logf(e + 1e-10f);
    float p = partials[tid] + partials[tid + 1024];
    #pragma unroll
    for (int off = 32; off; off >>= 1) {
        t += __shfl_down(t, off);
        p += __shfl_down(p, off);
    }
    if ((tid & 63) == 0) { redE[tid >> 6] = t; redL[tid >> 6] = p; }
    __syncthreads();
    if (tid == 0) {
        float se = 0.0f, sl = 0.0f;
        #pragma unroll
        for (int i = 0; i < 16; i++) { se += redE[i]; sl += redL[i]; }
        *ppl_out = expf(se);
        *loss_out = BETA * sl / (float)((size_t)N_TOKENS * DIM);
    }
}

extern "C" void kernel_launch(void* const* d_in, const int* in_sizes, int n_in,
                              void* d_out, int out_size, void* d_ws, size_t ws_size,
                              hipStream_t stream) {
    const float* z = (const float*)d_in[0];
    const float* w = (const float*)d_in[1];
    float* out = (float*)d_out;

    // d_out layout (float): [0]=loss, [1..NT*D]=z_q_st, [..]=indices(float), [last]=perplexity
    float* loss_out = out;
    float* zq_out   = out + 1;
    float* idxf     = out + 1 + (size_t)N_TOKENS * DIM;
    float* ppl_out  = out + (out_size - 1);

    // ws layout: wn f32[1024] | counts i32[1024] | partials f32[2048]
    //            | keys u64[32768] @ byte 16384 | whiG/wloG fp16[1024*256] @ 278528
    float* wn       = (float*)d_ws;
    int*   counts   = (int*)d_ws + 1024;
    float* partials = (float*)d_ws + 2048;
    u64*   keys     = (u64*)((char*)d_ws + 16384);
    _Float16* whiG  = (_Float16*)((char*)d_ws + 16384 + (size_t)N_TOKENS * 8);
    _Float16* wloG  = whiG + (size_t)K_CODES * DIM;

    init_kernel<<<K_CODES, 64, 0, stream>>>(w, wn, counts, keys, whiG, wloG);
    argmin_kernel<<<4 * 256, 256, 0, stream>>>(z, whiG, wloG, wn, keys);
    gather_loss_kernel<<<2048, 256, 0, stream>>>(z, w, keys, zq_out, idxf, counts, partials);
    finalize_kernel<<<1, 1024, 0, stream>>>(counts, partials, loss_out, ppl_out);
}